// Round 2
// baseline (870.014 us; speedup 1.0000x reference)
//
#include <hip/hip_runtime.h>
#include <hip/hip_bf16.h>

// Performer-style linear attention: B=4, S=8192, H=768, NH=12, HD=64, M=64.
// Pipeline (all scratch in d_ws, ~269 MB):
//   K1 split hs -> bf16 hi/lo
//   K2 fold projection P into Wq/Wk  (Wqp = Wq * blockdiag(P))  [fp32]
//   K3 build transposed concat weights [Wqp|Wkp|Wv] and WoT as bf16 hi/lo + bias
//   K4 split-GEMM QKV with FUSED epilogue: q/k cols -> rowmax+exp -> qp/kp bf16;
//      v cols -> vb16 bf16.  (no fp32 QKV intermediate)
//   K5 kv summary: kvT[bh][d][m] = sum_n kp[n,m] v[n,d] (fp32 vector + atomics), ksum
//   K6 kvT -> bf16
//   K7 normalizer: norm[bh][s] = qp . ksum
//   K8 ctx = (qp @ kv) / (norm+eps) -> ctx bf16 hi/lo (reuses hs buffers)
//   K9 split-GEMM: out = ctx @ Wo + bo -> fp32 d_out

#define S_    8192
#define H_    768
#define NH_   12
#define NC2_  2304          // 3*H
#define EPS_  1e-6f

typedef unsigned short U16;
typedef short bf16x8 __attribute__((ext_vector_type(8)));
typedef float f32x4  __attribute__((ext_vector_type(4)));

__device__ __forceinline__ U16 f2b(float x) {            // fp32 -> bf16 RNE
  unsigned u = __float_as_uint(x);
  return (U16)((u + 0x7fffu + ((u >> 16) & 1u)) >> 16);
}
__device__ __forceinline__ float b2f(U16 h) {
  return __uint_as_float(((unsigned)h) << 16);
}
__device__ __forceinline__ void gl2lds16(const void* g, void* l) {
  // async global->LDS, 16B/lane; LDS dest = wave-uniform base + lane*16
  __builtin_amdgcn_global_load_lds(
      (const __attribute__((address_space(1))) void*)g,
      (__attribute__((address_space(3))) void*)l, 16, 0, 0);
}

// ---------- zero scratch ----------
__global__ void zero_f32(float* __restrict__ p, int n) {
  int i = blockIdx.x * 256 + threadIdx.x;
  if (i < n) p[i] = 0.f;
}

// ---------- K1: split fp32 -> bf16 hi/lo ----------
__global__ void split_f32_bf16(const float* __restrict__ src,
                               U16* __restrict__ hi, U16* __restrict__ lo, int n4) {
  int i = blockIdx.x * 256 + threadIdx.x;
  if (i >= n4) return;
  float4 x = ((const float4*)src)[i];
  ushort4 h, l;
  h.x = f2b(x.x); l.x = f2b(x.x - b2f(h.x));
  h.y = f2b(x.y); l.y = f2b(x.y - b2f(h.y));
  h.z = f2b(x.z); l.z = f2b(x.z - b2f(h.z));
  h.w = f2b(x.w); l.w = f2b(x.w - b2f(h.w));
  ((ushort4*)hi)[i] = h;
  ((ushort4*)lo)[i] = l;
}

// ---------- K2: fold P into Wq / Wk (and biases) ----------
// grid (192, 12, 2), block 256.  Wout[k, h*64+m] = sum_d W[k, h*64+d] * P[h,d,m]
__global__ void fold_proj(const float* __restrict__ Wq, const float* __restrict__ bq,
                          const float* __restrict__ Wk, const float* __restrict__ bk,
                          const float* __restrict__ P,
                          float* __restrict__ Wqp, float* __restrict__ bqp,
                          float* __restrict__ Wkp, float* __restrict__ bkp) {
  __shared__ float Pl[64 * 64];
  __shared__ float WL[4 * 64];
  int h = blockIdx.y, kc = blockIdx.x, tid = threadIdx.x;
  const float* W  = blockIdx.z ? Wk : Wq;
  const float* bb = blockIdx.z ? bk : bq;
  float* Wout = blockIdx.z ? Wkp : Wqp;
  float* bout = blockIdx.z ? bkp : bqp;
  const float4* P4 = (const float4*)(P + (size_t)h * 4096);
#pragma unroll
  for (int i = 0; i < 4; ++i) ((float4*)Pl)[tid + i * 256] = P4[tid + i * 256];
  WL[tid] = W[(size_t)(kc * 4 + (tid >> 6)) * H_ + h * 64 + (tid & 63)];
  __syncthreads();
  int kl = tid >> 6, m = tid & 63;
  float acc = 0.f;
#pragma unroll
  for (int d = 0; d < 64; ++d) acc += WL[kl * 64 + d] * Pl[d * 64 + m];
  Wout[(size_t)(kc * 4 + kl) * H_ + h * 64 + m] = acc;
  if (kc == 0 && tid < 64) {
    float a2 = 0.f;
    for (int d = 0; d < 64; ++d) a2 += bb[h * 64 + d] * Pl[d * 64 + tid];
    bout[h * 64 + tid] = a2;
  }
}

// ---------- K3: build B^T-layout weights as bf16 hi/lo ----------
__global__ void build_cat(const float* __restrict__ Wqp, const float* __restrict__ Wkp,
                          const float* __restrict__ Wv,  const float* __restrict__ Wo,
                          U16* __restrict__ WcatH, U16* __restrict__ WcatL,
                          U16* __restrict__ WoTH,  U16* __restrict__ WoTL) {
  int k = blockIdx.x * 256 + threadIdx.x;
  int r = blockIdx.y;
  float v; U16 *dh, *dl; size_t off;
  if (r < 768)       { v = Wqp[(size_t)k * H_ + r];          off = (size_t)r * H_ + k;          dh = WcatH; dl = WcatL; }
  else if (r < 1536) { v = Wkp[(size_t)k * H_ + (r - 768)];  off = (size_t)r * H_ + k;          dh = WcatH; dl = WcatL; }
  else if (r < 2304) { v = Wv [(size_t)k * H_ + (r - 1536)]; off = (size_t)r * H_ + k;          dh = WcatH; dl = WcatL; }
  else               { v = Wo [(size_t)k * H_ + (r - 2304)]; off = (size_t)(r - 2304) * H_ + k; dh = WoTH;  dl = WoTL; }
  U16 h = f2b(v);
  dh[off] = h;
  dl[off] = f2b(v - b2f(h));
}

__global__ void build_bias(const float* __restrict__ bqp, const float* __restrict__ bkp,
                           const float* __restrict__ bv, float* __restrict__ biasC) {
  int i = blockIdx.x * 256 + threadIdx.x;
  if (i >= 2304) return;
  biasC[i] = i < 768 ? bqp[i] : (i < 1536 ? bkp[i - 768] : bv[i - 1536]);
}

// ---------- K4: split-3 GEMM + fused maxexp epilogue ----------
// A[32768,768]=Ahi+Alo, B[2304,768]=Bhi+Blo (B^T layout). 128x128 tile, BK=32,
// 4 waves x (4x4) mfma_16x16x32_bf16. Each wave's 64-col half is one head block:
// q/k cols -> bias + rowmax + exp -> qp/kp bf16 [bh][s][64]; v cols -> vb16 [row][768].
__global__ __launch_bounds__(256, 2) void gemm_qkv(
    const U16* __restrict__ Ahi, const U16* __restrict__ Alo,
    const U16* __restrict__ Bhi, const U16* __restrict__ Blo,
    const float* __restrict__ bias,
    U16* __restrict__ qp, U16* __restrict__ kp, U16* __restrict__ vb16) {
  __shared__ __align__(16) U16 AsH[128 * 32], AsL[128 * 32], BsH[128 * 32], BsL[128 * 32];
  const int tid = threadIdx.x, w = tid >> 6, lane = tid & 63;
  const int quad = lane >> 4, l16 = lane & 15;
  const int rowA0 = blockIdx.y * 128, colB0 = blockIdx.x * 128;
  const int wm = w & 1, wn = w >> 1;
  const int K = 768;
  f32x4 acc[4][4] = {};
  const int ch0 = (2 * w + 0) * 64 + lane, ch1 = (2 * w + 1) * 64 + lane;
  const int cb0 = (2 * w + 0) * 64, cb1 = (2 * w + 1) * 64;
  const size_t a0 = (size_t)(rowA0 + (ch0 >> 2)) * K + (ch0 & 3) * 8;
  const size_t a1 = (size_t)(rowA0 + (ch1 >> 2)) * K + (ch1 & 3) * 8;
  const size_t b0 = (size_t)(colB0 + (ch0 >> 2)) * K + (ch0 & 3) * 8;
  const size_t b1 = (size_t)(colB0 + (ch1 >> 2)) * K + (ch1 & 3) * 8;
  for (int k0 = 0; k0 < K; k0 += 32) {
    gl2lds16(Ahi + a0 + k0, &AsH[cb0 * 8]);
    gl2lds16(Ahi + a1 + k0, &AsH[cb1 * 8]);
    gl2lds16(Alo + a0 + k0, &AsL[cb0 * 8]);
    gl2lds16(Alo + a1 + k0, &AsL[cb1 * 8]);
    gl2lds16(Bhi + b0 + k0, &BsH[cb0 * 8]);
    gl2lds16(Bhi + b1 + k0, &BsH[cb1 * 8]);
    gl2lds16(Blo + b0 + k0, &BsL[cb0 * 8]);
    gl2lds16(Blo + b1 + k0, &BsL[cb1 * 8]);
    __syncthreads();
    bf16x8 ah[4], al[4];
#pragma unroll
    for (int i = 0; i < 4; ++i) {
      int mr = (wm * 64 + i * 16 + l16) * 32 + quad * 8;
      ah[i] = *(const bf16x8*)&AsH[mr];
      al[i] = *(const bf16x8*)&AsL[mr];
    }
#pragma unroll
    for (int j = 0; j < 4; ++j) {
      int nr = (wn * 64 + j * 16 + l16) * 32 + quad * 8;
      bf16x8 bh = *(const bf16x8*)&BsH[nr];
      bf16x8 bl = *(const bf16x8*)&BsL[nr];
#pragma unroll
      for (int i = 0; i < 4; ++i) {
        acc[i][j] = __builtin_amdgcn_mfma_f32_16x16x32_bf16(ah[i], bh, acc[i][j], 0, 0, 0);
        acc[i][j] = __builtin_amdgcn_mfma_f32_16x16x32_bf16(al[i], bh, acc[i][j], 0, 0, 0);
        acc[i][j] = __builtin_amdgcn_mfma_f32_16x16x32_bf16(ah[i], bl, acc[i][j], 0, 0, 0);
      }
    }
    __syncthreads();
  }
  // epilogue
  const int col64 = colB0 + wn * 64;            // 64-col half == one head block
  float bj[4];
#pragma unroll
  for (int j = 0; j < 4; ++j) bj[j] = bias[col64 + j * 16 + l16];
  if (col64 < 1536) {                           // q or k logits
    const int t = col64 >= 768;
    const int h = (col64 - t * 768) >> 6;
    U16* dst = t ? kp : qp;
#pragma unroll
    for (int i = 0; i < 4; ++i) {
#pragma unroll
      for (int r = 0; r < 4; ++r) {
        int row = rowA0 + wm * 64 + i * 16 + quad * 4 + r;
        float v0 = acc[i][0][r] + bj[0], v1 = acc[i][1][r] + bj[1];
        float v2 = acc[i][2][r] + bj[2], v3 = acc[i][3][r] + bj[3];
        float mx = fmaxf(fmaxf(v0, v1), fmaxf(v2, v3));
        mx = fmaxf(mx, __shfl_xor(mx, 1));
        mx = fmaxf(mx, __shfl_xor(mx, 2));
        mx = fmaxf(mx, __shfl_xor(mx, 4));
        mx = fmaxf(mx, __shfl_xor(mx, 8));
        int b = row >> 13, s = row & 8191;
        size_t base = ((size_t)(b * NH_ + h) * S_ + s) * 64 + l16;
        dst[base +  0] = f2b(__expf(v0 - mx));
        dst[base + 16] = f2b(__expf(v1 - mx));
        dst[base + 32] = f2b(__expf(v2 - mx));
        dst[base + 48] = f2b(__expf(v3 - mx));
      }
    }
  } else {                                      // v
#pragma unroll
    for (int i = 0; i < 4; ++i) {
#pragma unroll
      for (int r = 0; r < 4; ++r) {
        int row = rowA0 + wm * 64 + i * 16 + quad * 4 + r;
        size_t base = (size_t)row * H_ + (col64 - 1536) + l16;
#pragma unroll
        for (int j = 0; j < 4; ++j)
          vb16[base + j * 16] = f2b(acc[i][j][r] + bj[j]);
      }
    }
  }
}

// ---------- K9: split-precision bf16 GEMM (output projection) ----------
__global__ __launch_bounds__(256, 2) void gemm_split3(
    const U16* __restrict__ Ahi, const U16* __restrict__ Alo,
    const U16* __restrict__ Bhi, const U16* __restrict__ Blo,
    const float* __restrict__ bias, float* __restrict__ C, int K, int ldc) {
  __shared__ __align__(16) U16 AsH[128 * 32], AsL[128 * 32], BsH[128 * 32], BsL[128 * 32];
  const int tid = threadIdx.x, w = tid >> 6, lane = tid & 63;
  const int quad = lane >> 4, l16 = lane & 15;
  const int rowA0 = blockIdx.y * 128, colB0 = blockIdx.x * 128;
  const int wm = w & 1, wn = w >> 1;
  f32x4 acc[4][4] = {};
  const int ch0 = (2 * w + 0) * 64 + lane, ch1 = (2 * w + 1) * 64 + lane;
  const int cb0 = (2 * w + 0) * 64, cb1 = (2 * w + 1) * 64;
  const size_t a0 = (size_t)(rowA0 + (ch0 >> 2)) * K + (ch0 & 3) * 8;
  const size_t a1 = (size_t)(rowA0 + (ch1 >> 2)) * K + (ch1 & 3) * 8;
  const size_t b0 = (size_t)(colB0 + (ch0 >> 2)) * K + (ch0 & 3) * 8;
  const size_t b1 = (size_t)(colB0 + (ch1 >> 2)) * K + (ch1 & 3) * 8;
  for (int k0 = 0; k0 < K; k0 += 32) {
    gl2lds16(Ahi + a0 + k0, &AsH[cb0 * 8]);
    gl2lds16(Ahi + a1 + k0, &AsH[cb1 * 8]);
    gl2lds16(Alo + a0 + k0, &AsL[cb0 * 8]);
    gl2lds16(Alo + a1 + k0, &AsL[cb1 * 8]);
    gl2lds16(Bhi + b0 + k0, &BsH[cb0 * 8]);
    gl2lds16(Bhi + b1 + k0, &BsH[cb1 * 8]);
    gl2lds16(Blo + b0 + k0, &BsL[cb0 * 8]);
    gl2lds16(Blo + b1 + k0, &BsL[cb1 * 8]);
    __syncthreads();
    bf16x8 ah[4], al[4];
#pragma unroll
    for (int i = 0; i < 4; ++i) {
      int mr = (wm * 64 + i * 16 + l16) * 32 + quad * 8;
      ah[i] = *(const bf16x8*)&AsH[mr];
      al[i] = *(const bf16x8*)&AsL[mr];
    }
#pragma unroll
    for (int j = 0; j < 4; ++j) {
      int nr = (wn * 64 + j * 16 + l16) * 32 + quad * 8;
      bf16x8 bh = *(const bf16x8*)&BsH[nr];
      bf16x8 bl = *(const bf16x8*)&BsL[nr];
#pragma unroll
      for (int i = 0; i < 4; ++i) {
        acc[i][j] = __builtin_amdgcn_mfma_f32_16x16x32_bf16(ah[i], bh, acc[i][j], 0, 0, 0);
        acc[i][j] = __builtin_amdgcn_mfma_f32_16x16x32_bf16(al[i], bh, acc[i][j], 0, 0, 0);
        acc[i][j] = __builtin_amdgcn_mfma_f32_16x16x32_bf16(ah[i], bl, acc[i][j], 0, 0, 0);
      }
    }
    __syncthreads();
  }
#pragma unroll
  for (int i = 0; i < 4; ++i) {
    int row = rowA0 + wm * 64 + i * 16 + quad * 4;
#pragma unroll
    for (int j = 0; j < 4; ++j) {
      int col = colB0 + wn * 64 + j * 16 + l16;
      float bvv = bias[col];
#pragma unroll
      for (int r = 0; r < 4; ++r)
        C[(size_t)(row + r) * ldc + col] = acc[i][j][r] + bvv;
    }
  }
}

// ---------- K5: kv summary (fp32 vector, split-N atomics) ----------
// grid (8, 48): kvT[bh][d][m] += sum_n kp[n,m]*v[n,d];  ksum[bh][m] += sum_n kp[n,m]
__global__ void kv_accum_k(const U16* __restrict__ kp, const U16* __restrict__ vb16,
                           float* __restrict__ kvT, float* __restrict__ ksum) {
  __shared__ float kpL[32][64];
  __shared__ float vL[32][64];
  int bh = blockIdx.y, b = bh / NH_, h = bh - b * NH_;
  int n0 = blockIdx.x * 1024;
  int tid = threadIdx.x, m = tid >> 2, g = tid & 3;
  float c[16] = {};
  float cs = 0.f;
  const U16* kpb = kp + (size_t)bh * S_ * 64;
  const U16* vb = vb16 + (size_t)b * S_ * H_ + h * 64;
  int rr = tid >> 3, cc = (tid & 7) * 8;
  for (int nc = 0; nc < 1024; nc += 32) {
    __syncthreads();
    {
      const U16* s4 = kpb + (size_t)(n0 + nc + rr) * 64 + cc;
      ushort4 u0 = *(const ushort4*)s4, u1 = *(const ushort4*)(s4 + 4);
      float* d = &kpL[rr][cc];
      d[0] = b2f(u0.x); d[1] = b2f(u0.y); d[2] = b2f(u0.z); d[3] = b2f(u0.w);
      d[4] = b2f(u1.x); d[5] = b2f(u1.y); d[6] = b2f(u1.z); d[7] = b2f(u1.w);
      const U16* sv = vb + (size_t)(n0 + nc + rr) * H_ + cc;
      ushort4 f0 = *(const ushort4*)sv, f1 = *(const ushort4*)(sv + 4);
      float* dv = &vL[rr][cc];
      dv[0] = b2f(f0.x); dv[1] = b2f(f0.y); dv[2] = b2f(f0.z); dv[3] = b2f(f0.w);
      dv[4] = b2f(f1.x); dv[5] = b2f(f1.y); dv[6] = b2f(f1.z); dv[7] = b2f(f1.w);
    }
    __syncthreads();
#pragma unroll 4
    for (int n = 0; n < 32; ++n) {
      float kv_ = kpL[n][m];
      cs += kv_;
      const float* vr = &vL[n][g * 16];
#pragma unroll
      for (int i = 0; i < 16; i += 4) {
        float4 vv = *(const float4*)(vr + i);
        c[i + 0] += kv_ * vv.x; c[i + 1] += kv_ * vv.y;
        c[i + 2] += kv_ * vv.z; c[i + 3] += kv_ * vv.w;
      }
    }
  }
#pragma unroll
  for (int i = 0; i < 16; ++i)
    atomicAdd(&kvT[((size_t)bh * 64 + g * 16 + i) * 64 + m], c[i]);
  if (g == 0) atomicAdd(&ksum[bh * 64 + m], cs);
}

// ---------- K6: kvT fp32 -> bf16 ----------
__global__ void cvt_kv(const float* __restrict__ kvT, U16* __restrict__ kvb, int n4) {
  int i = blockIdx.x * 256 + threadIdx.x;
  if (i >= n4) return;
  float4 x = ((const float4*)kvT)[i];
  ushort4 o;
  o.x = f2b(x.x); o.y = f2b(x.y); o.z = f2b(x.z); o.w = f2b(x.w);
  ((ushort4*)kvb)[i] = o;
}

// ---------- K7: normalizer norm[bh][s] = qp . ksum ----------
__global__ void norm_k(const U16* __restrict__ qp, const float* __restrict__ ksum,
                       float* __restrict__ normv) {
  __shared__ float ks[64];
  int tid = threadIdx.x, qw = tid >> 4, l = tid & 15;
  int rowbase = blockIdx.x * 64;
  int bh = rowbase >> 13;
  if (tid < 64) ks[tid] = ksum[bh * 64 + tid];
  __syncthreads();
  float4 kk = *(const float4*)&ks[l * 4];
#pragma unroll
  for (int it = 0; it < 4; ++it) {
    int row = rowbase + it * 16 + qw;
    ushort4 u = *(const ushort4*)(qp + (size_t)row * 64 + l * 4);
    float acc = b2f(u.x) * kk.x + b2f(u.y) * kk.y + b2f(u.z) * kk.z + b2f(u.w) * kk.w;
    acc += __shfl_xor(acc, 1);
    acc += __shfl_xor(acc, 2);
    acc += __shfl_xor(acc, 4);
    acc += __shfl_xor(acc, 8);
    if (l == 0) normv[row] = acc;
  }
}

// ---------- K8: ctx = (qp @ kv) / (norm + eps), write bf16 hi/lo ----------
__global__ __launch_bounds__(256) void ctx_gemm_k(
    const U16* __restrict__ qp, const U16* __restrict__ kvb,
    const float* __restrict__ normv,
    U16* __restrict__ ctx_hi, U16* __restrict__ ctx_lo) {
  __shared__ __align__(16) U16 As[128 * 64];
  __shared__ __align__(16) U16 Bs[64 * 64];
  int bh = blockIdx.y, row0 = blockIdx.x * 128;
  int tid = threadIdx.x, w = tid >> 6, lane = tid & 63;
  int quad = lane >> 4, l16 = lane & 15;
  const U16* Ab = qp + ((size_t)bh * S_ + row0) * 64;
  const U16* Bb = kvb + (size_t)bh * 4096;
#pragma unroll
  for (int t = 0; t < 4; ++t) {
    int cb = (w * 4 + t) * 64;
    gl2lds16(Ab + (size_t)(cb + lane) * 8, &As[cb * 8]);
  }
#pragma unroll
  for (int t = 0; t < 2; ++t) {
    int cb = (w * 2 + t) * 64;
    gl2lds16(Bb + (size_t)(cb + lane) * 8, &Bs[cb * 8]);
  }
  __syncthreads();
  f32x4 acc[2][4] = {};
#pragma unroll
  for (int k0 = 0; k0 < 64; k0 += 32) {
    bf16x8 a[2], fb[4];
#pragma unroll
    for (int i = 0; i < 2; ++i)
      a[i] = *(const bf16x8*)&As[(w * 32 + i * 16 + l16) * 64 + k0 + quad * 8];
#pragma unroll
    for (int j = 0; j < 4; ++j)
      fb[j] = *(const bf16x8*)&Bs[(j * 16 + l16) * 64 + k0 + quad * 8];
#pragma unroll
    for (int j = 0; j < 4; ++j)
#pragma unroll
      for (int i = 0; i < 2; ++i)
        acc[i][j] = __builtin_amdgcn_mfma_f32_16x16x32_bf16(a[i], fb[j], acc[i][j], 0, 0, 0);
  }
  int b = bh / NH_, h = bh - b * NH_;
#pragma unroll
  for (int i = 0; i < 2; ++i) {
#pragma unroll
    for (int r = 0; r < 4; ++r) {
      int s = row0 + w * 32 + i * 16 + quad * 4 + r;
      float inv = 1.f / (normv[(size_t)bh * S_ + s] + EPS_);
#pragma unroll
      for (int j = 0; j < 4; ++j) {
        int d = j * 16 + l16;
        float v = acc[i][j][r] * inv;
        size_t off = ((size_t)b * S_ + s) * H_ + h * 64 + d;
        U16 hh = f2b(v);
        ctx_hi[off] = hh;
        ctx_lo[off] = f2b(v - b2f(hh));
      }
    }
  }
}

extern "C" void kernel_launch(void* const* d_in, const int* in_sizes, int n_in,
                              void* d_out, int out_size, void* d_ws, size_t ws_size,
                              hipStream_t stream) {
  const float* hs = (const float*)d_in[0];
  const float* Wq = (const float*)d_in[1];
  const float* bq = (const float*)d_in[2];
  const float* Wk = (const float*)d_in[3];
  const float* bk = (const float*)d_in[4];
  const float* Wv = (const float*)d_in[5];
  const float* bv = (const float*)d_in[6];
  const float* Wo = (const float*)d_in[7];
  const float* bo = (const float*)d_in[8];
  const float* P  = (const float*)d_in[9];
  float* out = (float*)d_out;

  char* ws = (char*)d_ws;
  size_t off = 0;
  auto alloc = [&](size_t bytes) -> void* {
    void* p = ws + off;
    off = (off + bytes + 255) & ~(size_t)255;
    return p;
  };
  U16*   hs_hi = (U16*)alloc(50331648);     // [32768,768] bf16
  U16*   hs_lo = (U16*)alloc(50331648);
  float* WqpF  = (float*)alloc(2359296);
  float* WkpF  = (float*)alloc(2359296);
  float* bqpF  = (float*)alloc(3072);
  float* bkpF  = (float*)alloc(3072);
  U16*   WcatH = (U16*)alloc(3538944);      // [2304,768] bf16
  U16*   WcatL = (U16*)alloc(3538944);
  U16*   WoTH  = (U16*)alloc(1179648);
  U16*   WoTL  = (U16*)alloc(1179648);
  float* biasC = (float*)alloc(9216);
  U16*   qp    = (U16*)alloc(50331648);     // [48,8192,64] bf16
  U16*   kp    = (U16*)alloc(50331648);
  U16*   vb16  = (U16*)alloc(50331648);     // [32768,768] bf16
  float* kvT   = (float*)alloc(786432);     // [48,64,64] fp32
  float* ksum  = (float*)alloc(12288);      // [48,64] fp32 (contiguous after kvT)
  U16*   kvb   = (U16*)alloc(393216);
  float* normv = (float*)alloc(1572864);
  U16*   ctx_hi = hs_hi;                    // hs dead after the QKV GEMM: reuse
  U16*   ctx_lo = hs_lo;

  zero_f32<<<dim3(780), dim3(256), 0, stream>>>(kvT, 199680);   // kvT + ksum
  split_f32_bf16<<<dim3(24576), dim3(256), 0, stream>>>(hs, hs_hi, hs_lo, 6291456);
  fold_proj<<<dim3(192, 12, 2), dim3(256), 0, stream>>>(Wq, bq, Wk, bk, P, WqpF, bqpF, WkpF, bkpF);
  build_cat<<<dim3(3, 3072), dim3(256), 0, stream>>>(WqpF, WkpF, Wv, Wo, WcatH, WcatL, WoTH, WoTL);
  build_bias<<<dim3(9), dim3(256), 0, stream>>>(bqpF, bkpF, bv, biasC);
  gemm_qkv<<<dim3(18, 256), dim3(256), 0, stream>>>(hs_hi, hs_lo, WcatH, WcatL, biasC, qp, kp, vb16);
  kv_accum_k<<<dim3(8, 48), dim3(256), 0, stream>>>(kp, vb16, kvT, ksum);
  cvt_kv<<<dim3(192), dim3(256), 0, stream>>>(kvT, kvb, 49152);
  norm_k<<<dim3(6144), dim3(256), 0, stream>>>(qp, ksum, normv);
  ctx_gemm_k<<<dim3(64, 48), dim3(256), 0, stream>>>(qp, kvb, normv, ctx_hi, ctx_lo);
  gemm_split3<<<dim3(6, 256), dim3(256), 0, stream>>>(ctx_hi, ctx_lo, WoTH, WoTL, bo, out, 768, 768);
}

// Round 3
// 670.050 us; speedup vs baseline: 1.2984x; 1.2984x over previous
//
#include <hip/hip_runtime.h>
#include <hip/hip_bf16.h>

// Performer-style linear attention: B=4, S=8192, H=768, NH=12, HD=64, M=64.
// Round 3: 2-term split GEMMs (A single bf16, B=weights hi/lo), fused
// normalizer-as-MFMA-column in ctx_gemm, ksum folded into kvT row 64.
// Pipeline:
//   K0 zero kvT[48][80][64]
//   K1 cvt hs -> bf16
//   K2 fold projection P into Wq/Wk  (Wqp = Wq * blockdiag(P))  [fp32]
//   K3 build transposed concat weights [Wqp|Wkp|Wv] and WoT as bf16 hi/lo + bias
//   K4 2-term GEMM QKV + fused maxexp epilogue -> qp/kp/vb16 (bf16)
//   K5 kv summary: kvT[bh][d][m] += sum_n kp[n,m] v[n,d]; row 64 = ksum
//   K6 ctx_gemm: acc = qp @ [kvT | ksum]^T (5 col tiles), norm from tile 4,
//      ctx = acc/(norm+eps) -> ctx bf16 (reuses hs buffer)
//   K7 2-term GEMM: out = ctx @ Wo + bo -> fp32 d_out

#define S_    8192
#define H_    768
#define NH_   12
#define EPS_  1e-6f

typedef unsigned short U16;
typedef short bf16x8 __attribute__((ext_vector_type(8)));
typedef float f32x4  __attribute__((ext_vector_type(4)));

__device__ __forceinline__ U16 f2b(float x) {            // fp32 -> bf16 RNE
  unsigned u = __float_as_uint(x);
  return (U16)((u + 0x7fffu + ((u >> 16) & 1u)) >> 16);
}
__device__ __forceinline__ float b2f(U16 h) {
  return __uint_as_float(((unsigned)h) << 16);
}
__device__ __forceinline__ void gl2lds16(const void* g, void* l) {
  __builtin_amdgcn_global_load_lds(
      (const __attribute__((address_space(1))) void*)g,
      (__attribute__((address_space(3))) void*)l, 16, 0, 0);
}

// ---------- K0: zero scratch ----------
__global__ void zero_f32(float* __restrict__ p, int n) {
  int i = blockIdx.x * 256 + threadIdx.x;
  if (i < n) p[i] = 0.f;
}

// ---------- K1: fp32 -> bf16 ----------
__global__ void cvt_f32_bf16(const float* __restrict__ src, U16* __restrict__ hi, int n4) {
  int i = blockIdx.x * 256 + threadIdx.x;
  if (i >= n4) return;
  float4 x = ((const float4*)src)[i];
  ushort4 h;
  h.x = f2b(x.x); h.y = f2b(x.y); h.z = f2b(x.z); h.w = f2b(x.w);
  ((ushort4*)hi)[i] = h;
}

// ---------- K2: fold P into Wq / Wk (and biases) ----------
__global__ void fold_proj(const float* __restrict__ Wq, const float* __restrict__ bq,
                          const float* __restrict__ Wk, const float* __restrict__ bk,
                          const float* __restrict__ P,
                          float* __restrict__ Wqp, float* __restrict__ bqp,
                          float* __restrict__ Wkp, float* __restrict__ bkp) {
  __shared__ float Pl[64 * 64];
  __shared__ float WL[4 * 64];
  int h = blockIdx.y, kc = blockIdx.x, tid = threadIdx.x;
  const float* W  = blockIdx.z ? Wk : Wq;
  const float* bb = blockIdx.z ? bk : bq;
  float* Wout = blockIdx.z ? Wkp : Wqp;
  float* bout = blockIdx.z ? bkp : bqp;
  const float4* P4 = (const float4*)(P + (size_t)h * 4096);
#pragma unroll
  for (int i = 0; i < 4; ++i) ((float4*)Pl)[tid + i * 256] = P4[tid + i * 256];
  WL[tid] = W[(size_t)(kc * 4 + (tid >> 6)) * H_ + h * 64 + (tid & 63)];
  __syncthreads();
  int kl = tid >> 6, m = tid & 63;
  float acc = 0.f;
#pragma unroll
  for (int d = 0; d < 64; ++d) acc += WL[kl * 64 + d] * Pl[d * 64 + m];
  Wout[(size_t)(kc * 4 + kl) * H_ + h * 64 + m] = acc;
  if (kc == 0 && tid < 64) {
    float a2 = 0.f;
    for (int d = 0; d < 64; ++d) a2 += bb[h * 64 + d] * Pl[d * 64 + tid];
    bout[h * 64 + tid] = a2;
  }
}

// ---------- K3: build B^T-layout weights as bf16 hi/lo ----------
__global__ void build_cat(const float* __restrict__ Wqp, const float* __restrict__ Wkp,
                          const float* __restrict__ Wv,  const float* __restrict__ Wo,
                          U16* __restrict__ WcatH, U16* __restrict__ WcatL,
                          U16* __restrict__ WoTH,  U16* __restrict__ WoTL) {
  int k = blockIdx.x * 256 + threadIdx.x;
  int r = blockIdx.y;
  float v; U16 *dh, *dl; size_t off;
  if (r < 768)       { v = Wqp[(size_t)k * H_ + r];          off = (size_t)r * H_ + k;          dh = WcatH; dl = WcatL; }
  else if (r < 1536) { v = Wkp[(size_t)k * H_ + (r - 768)];  off = (size_t)r * H_ + k;          dh = WcatH; dl = WcatL; }
  else if (r < 2304) { v = Wv [(size_t)k * H_ + (r - 1536)]; off = (size_t)r * H_ + k;          dh = WcatH; dl = WcatL; }
  else               { v = Wo [(size_t)k * H_ + (r - 2304)]; off = (size_t)(r - 2304) * H_ + k; dh = WoTH;  dl = WoTL; }
  U16 h = f2b(v);
  dh[off] = h;
  dl[off] = f2b(v - b2f(h));
}

__global__ void build_bias(const float* __restrict__ bqp, const float* __restrict__ bkp,
                           const float* __restrict__ bv, float* __restrict__ biasC) {
  int i = blockIdx.x * 256 + threadIdx.x;
  if (i >= 2304) return;
  biasC[i] = i < 768 ? bqp[i] : (i < 1536 ? bkp[i - 768] : bv[i - 1536]);
}

// ---------- K4: 2-term split GEMM + fused maxexp epilogue ----------
// C = A_bf16 @ (Bh+Bl)^T + bias.  Unified LDS: Us[0:4096]=A, [4096:8192]=Bh,
// [8192:12288]=Bl (U16 units).  24 staging chunks/iter, 6 per wave.
__global__ __launch_bounds__(256, 4) void gemm_qkv(
    const U16* __restrict__ Ahi,
    const U16* __restrict__ Bhi, const U16* __restrict__ Blo,
    const float* __restrict__ bias,
    U16* __restrict__ qp, U16* __restrict__ kp, U16* __restrict__ vb16) {
  __shared__ __align__(16) U16 Us[3 * 128 * 32];
  const int tid = threadIdx.x, w = tid >> 6, lane = tid & 63;
  const int quad = lane >> 4, l16 = lane & 15;
  const int rowA0 = blockIdx.y * 128, colB0 = blockIdx.x * 128;
  const int wm = w & 1, wn = w >> 1;
  const int K = 768;
  f32x4 acc[4][4] = {};
  const U16* srcs[6];
  unsigned ldsoff[6];
#pragma unroll
  for (int t = 0; t < 6; ++t) {
    int c = w * 6 + t, cc = c & 7, buf = c >> 3;
    const U16* base = buf == 0 ? Ahi : (buf == 1 ? Bhi : Blo);
    int r0 = buf == 0 ? rowA0 : colB0;
    srcs[t] = base + (size_t)(r0 + cc * 16 + (lane >> 2)) * K + (lane & 3) * 8;
    ldsoff[t] = c * 512;
  }
  for (int k0 = 0; k0 < K; k0 += 32) {
#pragma unroll
    for (int t = 0; t < 6; ++t) gl2lds16(srcs[t] + k0, &Us[ldsoff[t]]);
    __syncthreads();
    bf16x8 ah[4];
#pragma unroll
    for (int i = 0; i < 4; ++i)
      ah[i] = *(const bf16x8*)&Us[(wm * 64 + i * 16 + l16) * 32 + quad * 8];
#pragma unroll
    for (int j = 0; j < 4; ++j) {
      int nr = (wn * 64 + j * 16 + l16) * 32 + quad * 8;
      bf16x8 bh = *(const bf16x8*)&Us[4096 + nr];
      bf16x8 bl = *(const bf16x8*)&Us[8192 + nr];
#pragma unroll
      for (int i = 0; i < 4; ++i) {
        acc[i][j] = __builtin_amdgcn_mfma_f32_16x16x32_bf16(ah[i], bh, acc[i][j], 0, 0, 0);
        acc[i][j] = __builtin_amdgcn_mfma_f32_16x16x32_bf16(ah[i], bl, acc[i][j], 0, 0, 0);
      }
    }
    __syncthreads();
  }
  // epilogue: each wave's 64-col half is one head block
  const int col64 = colB0 + wn * 64;
  float bj[4];
#pragma unroll
  for (int j = 0; j < 4; ++j) bj[j] = bias[col64 + j * 16 + l16];
  if (col64 < 1536) {                           // q or k logits
    const int t = col64 >= 768;
    const int h = (col64 - t * 768) >> 6;
    U16* dst = t ? kp : qp;
#pragma unroll
    for (int i = 0; i < 4; ++i) {
#pragma unroll
      for (int r = 0; r < 4; ++r) {
        int row = rowA0 + wm * 64 + i * 16 + quad * 4 + r;
        float v0 = acc[i][0][r] + bj[0], v1 = acc[i][1][r] + bj[1];
        float v2 = acc[i][2][r] + bj[2], v3 = acc[i][3][r] + bj[3];
        float mx = fmaxf(fmaxf(v0, v1), fmaxf(v2, v3));
        mx = fmaxf(mx, __shfl_xor(mx, 1));
        mx = fmaxf(mx, __shfl_xor(mx, 2));
        mx = fmaxf(mx, __shfl_xor(mx, 4));
        mx = fmaxf(mx, __shfl_xor(mx, 8));
        int b = row >> 13, s = row & 8191;
        size_t base = ((size_t)(b * NH_ + h) * S_ + s) * 64 + l16;
        dst[base +  0] = f2b(__expf(v0 - mx));
        dst[base + 16] = f2b(__expf(v1 - mx));
        dst[base + 32] = f2b(__expf(v2 - mx));
        dst[base + 48] = f2b(__expf(v3 - mx));
      }
    }
  } else {                                      // v
#pragma unroll
    for (int i = 0; i < 4; ++i) {
#pragma unroll
      for (int r = 0; r < 4; ++r) {
        int row = rowA0 + wm * 64 + i * 16 + quad * 4 + r;
        size_t base = (size_t)row * H_ + (col64 - 1536) + l16;
#pragma unroll
        for (int j = 0; j < 4; ++j)
          vb16[base + j * 16] = f2b(acc[i][j][r] + bj[j]);
      }
    }
  }
}

// ---------- K7: 2-term split GEMM (output projection) ----------
__global__ __launch_bounds__(256, 4) void gemm_split2(
    const U16* __restrict__ Ahi,
    const U16* __restrict__ Bhi, const U16* __restrict__ Blo,
    const float* __restrict__ bias, float* __restrict__ C, int K, int ldc) {
  __shared__ __align__(16) U16 Us[3 * 128 * 32];
  const int tid = threadIdx.x, w = tid >> 6, lane = tid & 63;
  const int quad = lane >> 4, l16 = lane & 15;
  const int rowA0 = blockIdx.y * 128, colB0 = blockIdx.x * 128;
  const int wm = w & 1, wn = w >> 1;
  f32x4 acc[4][4] = {};
  const U16* srcs[6];
  unsigned ldsoff[6];
#pragma unroll
  for (int t = 0; t < 6; ++t) {
    int c = w * 6 + t, cc = c & 7, buf = c >> 3;
    const U16* base = buf == 0 ? Ahi : (buf == 1 ? Bhi : Blo);
    int r0 = buf == 0 ? rowA0 : colB0;
    srcs[t] = base + (size_t)(r0 + cc * 16 + (lane >> 2)) * K + (lane & 3) * 8;
    ldsoff[t] = c * 512;
  }
  for (int k0 = 0; k0 < K; k0 += 32) {
#pragma unroll
    for (int t = 0; t < 6; ++t) gl2lds16(srcs[t] + k0, &Us[ldsoff[t]]);
    __syncthreads();
    bf16x8 ah[4];
#pragma unroll
    for (int i = 0; i < 4; ++i)
      ah[i] = *(const bf16x8*)&Us[(wm * 64 + i * 16 + l16) * 32 + quad * 8];
#pragma unroll
    for (int j = 0; j < 4; ++j) {
      int nr = (wn * 64 + j * 16 + l16) * 32 + quad * 8;
      bf16x8 bh = *(const bf16x8*)&Us[4096 + nr];
      bf16x8 bl = *(const bf16x8*)&Us[8192 + nr];
#pragma unroll
      for (int i = 0; i < 4; ++i) {
        acc[i][j] = __builtin_amdgcn_mfma_f32_16x16x32_bf16(ah[i], bh, acc[i][j], 0, 0, 0);
        acc[i][j] = __builtin_amdgcn_mfma_f32_16x16x32_bf16(ah[i], bl, acc[i][j], 0, 0, 0);
      }
    }
    __syncthreads();
  }
#pragma unroll
  for (int i = 0; i < 4; ++i) {
    int row = rowA0 + wm * 64 + i * 16 + quad * 4;
#pragma unroll
    for (int j = 0; j < 4; ++j) {
      int col = colB0 + wn * 64 + j * 16 + l16;
      float bvv = bias[col];
#pragma unroll
      for (int r = 0; r < 4; ++r)
        C[(size_t)(row + r) * ldc + col] = acc[i][j][r] + bvv;
    }
  }
}

// ---------- K5: kv summary into kvT[bh][80][64]; row 64 = ksum ----------
__global__ void kv_accum_k(const U16* __restrict__ kp, const U16* __restrict__ vb16,
                           float* __restrict__ kvT) {
  __shared__ float kpL[32][64];
  __shared__ float vL[32][64];
  int bh = blockIdx.y, b = bh / NH_, h = bh - b * NH_;
  int n0 = blockIdx.x * 1024;
  int tid = threadIdx.x, m = tid >> 2, g = tid & 3;
  float c[16] = {};
  float cs = 0.f;
  const U16* kpb = kp + (size_t)bh * S_ * 64;
  const U16* vb = vb16 + (size_t)b * S_ * H_ + h * 64;
  int rr = tid >> 3, cc = (tid & 7) * 8;
  for (int nc = 0; nc < 1024; nc += 32) {
    __syncthreads();
    {
      const U16* s4 = kpb + (size_t)(n0 + nc + rr) * 64 + cc;
      ushort4 u0 = *(const ushort4*)s4, u1 = *(const ushort4*)(s4 + 4);
      float* d = &kpL[rr][cc];
      d[0] = b2f(u0.x); d[1] = b2f(u0.y); d[2] = b2f(u0.z); d[3] = b2f(u0.w);
      d[4] = b2f(u1.x); d[5] = b2f(u1.y); d[6] = b2f(u1.z); d[7] = b2f(u1.w);
      const U16* sv = vb + (size_t)(n0 + nc + rr) * H_ + cc;
      ushort4 f0 = *(const ushort4*)sv, f1 = *(const ushort4*)(sv + 4);
      float* dv = &vL[rr][cc];
      dv[0] = b2f(f0.x); dv[1] = b2f(f0.y); dv[2] = b2f(f0.z); dv[3] = b2f(f0.w);
      dv[4] = b2f(f1.x); dv[5] = b2f(f1.y); dv[6] = b2f(f1.z); dv[7] = b2f(f1.w);
    }
    __syncthreads();
#pragma unroll 4
    for (int n = 0; n < 32; ++n) {
      float kv_ = kpL[n][m];
      cs += kv_;
      const float* vr = &vL[n][g * 16];
#pragma unroll
      for (int i = 0; i < 16; i += 4) {
        float4 vv = *(const float4*)(vr + i);
        c[i + 0] += kv_ * vv.x; c[i + 1] += kv_ * vv.y;
        c[i + 2] += kv_ * vv.z; c[i + 3] += kv_ * vv.w;
      }
    }
  }
#pragma unroll
  for (int i = 0; i < 16; ++i)
    atomicAdd(&kvT[((size_t)bh * 80 + g * 16 + i) * 64 + m], c[i]);
  if (g == 0) atomicAdd(&kvT[((size_t)bh * 80 + 64) * 64 + m], cs);
}

// ---------- K6: ctx = (qp @ kv)/(norm+eps); norm = MFMA tile j=4 ----------
// B tile = kvT[bh] (80 rows x 64 k): rows 0..63 = kv^T, row 64 = ksum, 65..79 = 0.
__global__ __launch_bounds__(256) void ctx_gemm_k(
    const U16* __restrict__ qp, const float* __restrict__ kvT,
    U16* __restrict__ ctx) {
  __shared__ __align__(16) U16 As[128 * 64];
  __shared__ __align__(16) U16 Bs[80 * 64];
  int bh = blockIdx.y, row0 = blockIdx.x * 128;
  int tid = threadIdx.x, w = tid >> 6, lane = tid & 63;
  int quad = lane >> 4, l16 = lane & 15;
  const U16* Ab = qp + ((size_t)bh * S_ + row0) * 64;
#pragma unroll
  for (int t = 0; t < 4; ++t) {
    int cb = (w * 4 + t) * 64;
    gl2lds16(Ab + (size_t)(cb + lane) * 8, &As[cb * 8]);
  }
  const float4* kv4 = (const float4*)(kvT + (size_t)bh * 5120);
#pragma unroll
  for (int t = 0; t < 5; ++t) {
    int idx = t * 256 + tid;          // 0..1279 float4s = 80*64 floats
    float4 f = kv4[idx];
    ushort4 o;
    o.x = f2b(f.x); o.y = f2b(f.y); o.z = f2b(f.z); o.w = f2b(f.w);
    *(ushort4*)&Bs[idx * 4] = o;
  }
  __syncthreads();
  f32x4 acc[2][5] = {};
#pragma unroll
  for (int k0 = 0; k0 < 64; k0 += 32) {
    bf16x8 a[2], fb[5];
#pragma unroll
    for (int i = 0; i < 2; ++i)
      a[i] = *(const bf16x8*)&As[(w * 32 + i * 16 + l16) * 64 + k0 + quad * 8];
#pragma unroll
    for (int j = 0; j < 5; ++j)
      fb[j] = *(const bf16x8*)&Bs[(j * 16 + l16) * 64 + k0 + quad * 8];
#pragma unroll
    for (int j = 0; j < 5; ++j)
#pragma unroll
      for (int i = 0; i < 2; ++i)
        acc[i][j] = __builtin_amdgcn_mfma_f32_16x16x32_bf16(a[i], fb[j], acc[i][j], 0, 0, 0);
  }
  int b = bh / NH_, h = bh - b * NH_;
#pragma unroll
  for (int i = 0; i < 2; ++i) {
#pragma unroll
    for (int r = 0; r < 4; ++r) {
      int s = row0 + w * 32 + i * 16 + quad * 4 + r;
      float nv = __shfl(acc[i][4][r], lane & 48);   // col 64 (l16==0) = norm(row)
      float inv = 1.f / (nv + EPS_);
      size_t base = ((size_t)b * S_ + s) * H_ + h * 64;
#pragma unroll
      for (int j = 0; j < 4; ++j)
        ctx[base + j * 16 + l16] = f2b(acc[i][j][r] * inv);
    }
  }
}

extern "C" void kernel_launch(void* const* d_in, const int* in_sizes, int n_in,
                              void* d_out, int out_size, void* d_ws, size_t ws_size,
                              hipStream_t stream) {
  const float* hs = (const float*)d_in[0];
  const float* Wq = (const float*)d_in[1];
  const float* bq = (const float*)d_in[2];
  const float* Wk = (const float*)d_in[3];
  const float* bk = (const float*)d_in[4];
  const float* Wv = (const float*)d_in[5];
  const float* bv = (const float*)d_in[6];
  const float* Wo = (const float*)d_in[7];
  const float* bo = (const float*)d_in[8];
  const float* P  = (const float*)d_in[9];
  float* out = (float*)d_out;

  char* ws = (char*)d_ws;
  size_t off = 0;
  auto alloc = [&](size_t bytes) -> void* {
    void* p = ws + off;
    off = (off + bytes + 255) & ~(size_t)255;
    return p;
  };
  U16*   hs_hi = (U16*)alloc(50331648);     // [32768,768] bf16 (reused as ctx)
  float* WqpF  = (float*)alloc(2359296);
  float* WkpF  = (float*)alloc(2359296);
  float* bqpF  = (float*)alloc(3072);
  float* bkpF  = (float*)alloc(3072);
  U16*   WcatH = (U16*)alloc(3538944);      // [2304,768] bf16
  U16*   WcatL = (U16*)alloc(3538944);
  U16*   WoTH  = (U16*)alloc(1179648);
  U16*   WoTL  = (U16*)alloc(1179648);
  float* biasC = (float*)alloc(9216);
  U16*   qp    = (U16*)alloc(50331648);     // [48,8192,64] bf16
  U16*   kp    = (U16*)alloc(50331648);
  U16*   vb16  = (U16*)alloc(50331648);     // [32768,768] bf16
  float* kvT   = (float*)alloc(983040);     // [48,80,64] fp32 (row 64 = ksum)
  U16*   ctx   = hs_hi;                     // hs dead after QKV GEMM: reuse

  zero_f32<<<dim3(960), dim3(256), 0, stream>>>(kvT, 245760);
  cvt_f32_bf16<<<dim3(24576), dim3(256), 0, stream>>>(hs, hs_hi, 6291456);
  fold_proj<<<dim3(192, 12, 2), dim3(256), 0, stream>>>(Wq, bq, Wk, bk, P, WqpF, bqpF, WkpF, bkpF);
  build_cat<<<dim3(3, 3072), dim3(256), 0, stream>>>(WqpF, WkpF, Wv, Wo, WcatH, WcatL, WoTH, WoTL);
  build_bias<<<dim3(9), dim3(256), 0, stream>>>(bqpF, bkpF, bv, biasC);
  gemm_qkv<<<dim3(18, 256), dim3(256), 0, stream>>>(hs_hi, WcatH, WcatL, biasC, qp, kp, vb16);
  kv_accum_k<<<dim3(8, 48), dim3(256), 0, stream>>>(kp, vb16, kvT);
  ctx_gemm_k<<<dim3(64, 48), dim3(256), 0, stream>>>(qp, kvT, ctx);
  gemm_split2<<<dim3(6, 256), dim3(256), 0, stream>>>(ctx, WoTH, WoTL, bo, out, 768, 768);
}

// Round 4
// 504.284 us; speedup vs baseline: 1.7252x; 1.3287x over previous
//
#include <hip/hip_runtime.h>
#include <hip/hip_bf16.h>

// Performer-style linear attention: B=4, S=8192, H=768, NH=12, HD=64, M=64.
// Round 4: single-bf16 GEMMs (weight-quant noise ~3e-4 on O(2) logits, invisible
// at the 2.93e-4 out-threshold given ratio cancellation); kp/v written TRANSPOSED
// in the QKV epilogue so the kv summary becomes a clean MFMA gemm_bt (K=8192).
// Pipeline:
//   K0 zero kvT[48][80][64]
//   K1 cvt hs -> bf16
//   K2 fold P into Wq/Wk (Wqp = Wq * blockdiag(P)) [fp32]
//   K3 build B^T concat weights [Wqp|Wkp|Wv] + WoT as bf16, bias
//   K4 bf16 GEMM QKV + fused maxexp epilogue -> qp [bh][s][64] row-major,
//      kpT [bh][m][n], vT [bh][d][n] transposed
//   K5 kv MFMA: kvT[bh][d][m] = sum_n vT[d][n] kpT[m][n]; row 64 = ksum (frag sums)
//   K6 ctx_gemm: acc = qp @ [kvT|ksum]^T (5 col tiles), norm = tile 4,
//      ctx = acc/(norm+eps) -> ctx bf16 (reuses hs buffer)
//   K7 bf16 GEMM: out = ctx @ Wo + bo -> fp32 d_out

#define S_    8192
#define H_    768
#define NH_   12
#define EPS_  1e-6f

typedef unsigned short U16;
typedef short bf16x8 __attribute__((ext_vector_type(8)));
typedef float f32x4  __attribute__((ext_vector_type(4)));

__device__ __forceinline__ U16 f2b(float x) {            // fp32 -> bf16 RNE
  unsigned u = __float_as_uint(x);
  return (U16)((u + 0x7fffu + ((u >> 16) & 1u)) >> 16);
}
__device__ __forceinline__ float b2f(U16 h) {
  return __uint_as_float(((unsigned)h) << 16);
}
__device__ __forceinline__ void gl2lds16(const void* g, void* l) {
  __builtin_amdgcn_global_load_lds(
      (const __attribute__((address_space(1))) void*)g,
      (__attribute__((address_space(3))) void*)l, 16, 0, 0);
}

// ---------- K0: zero scratch ----------
__global__ void zero_f32(float* __restrict__ p, int n) {
  int i = blockIdx.x * 256 + threadIdx.x;
  if (i < n) p[i] = 0.f;
}

// ---------- K1: fp32 -> bf16 ----------
__global__ void cvt_f32_bf16(const float* __restrict__ src, U16* __restrict__ hi, int n4) {
  int i = blockIdx.x * 256 + threadIdx.x;
  if (i >= n4) return;
  float4 x = ((const float4*)src)[i];
  ushort4 h;
  h.x = f2b(x.x); h.y = f2b(x.y); h.z = f2b(x.z); h.w = f2b(x.w);
  ((ushort4*)hi)[i] = h;
}

// ---------- K2: fold P into Wq / Wk (and biases) ----------
__global__ void fold_proj(const float* __restrict__ Wq, const float* __restrict__ bq,
                          const float* __restrict__ Wk, const float* __restrict__ bk,
                          const float* __restrict__ P,
                          float* __restrict__ Wqp, float* __restrict__ bqp,
                          float* __restrict__ Wkp, float* __restrict__ bkp) {
  __shared__ float Pl[64 * 64];
  __shared__ float WL[4 * 64];
  int h = blockIdx.y, kc = blockIdx.x, tid = threadIdx.x;
  const float* W  = blockIdx.z ? Wk : Wq;
  const float* bb = blockIdx.z ? bk : bq;
  float* Wout = blockIdx.z ? Wkp : Wqp;
  float* bout = blockIdx.z ? bkp : bqp;
  const float4* P4 = (const float4*)(P + (size_t)h * 4096);
#pragma unroll
  for (int i = 0; i < 4; ++i) ((float4*)Pl)[tid + i * 256] = P4[tid + i * 256];
  WL[tid] = W[(size_t)(kc * 4 + (tid >> 6)) * H_ + h * 64 + (tid & 63)];
  __syncthreads();
  int kl = tid >> 6, m = tid & 63;
  float acc = 0.f;
#pragma unroll
  for (int d = 0; d < 64; ++d) acc += WL[kl * 64 + d] * Pl[d * 64 + m];
  Wout[(size_t)(kc * 4 + kl) * H_ + h * 64 + m] = acc;
  if (kc == 0 && tid < 64) {
    float a2 = 0.f;
    for (int d = 0; d < 64; ++d) a2 += bb[h * 64 + d] * Pl[d * 64 + tid];
    bout[h * 64 + tid] = a2;
  }
}

// ---------- K3: build B^T-layout weights as bf16 ----------
__global__ void build_cat(const float* __restrict__ Wqp, const float* __restrict__ Wkp,
                          const float* __restrict__ Wv,  const float* __restrict__ Wo,
                          U16* __restrict__ WcatH, U16* __restrict__ WoTH) {
  int k = blockIdx.x * 256 + threadIdx.x;
  int r = blockIdx.y;
  float v; U16* dh; size_t off;
  if (r < 768)       { v = Wqp[(size_t)k * H_ + r];          off = (size_t)r * H_ + k;          dh = WcatH; }
  else if (r < 1536) { v = Wkp[(size_t)k * H_ + (r - 768)];  off = (size_t)r * H_ + k;          dh = WcatH; }
  else if (r < 2304) { v = Wv [(size_t)k * H_ + (r - 1536)]; off = (size_t)r * H_ + k;          dh = WcatH; }
  else               { v = Wo [(size_t)k * H_ + (r - 2304)]; off = (size_t)(r - 2304) * H_ + k; dh = WoTH; }
  dh[off] = f2b(v);
}

__global__ void build_bias(const float* __restrict__ bqp, const float* __restrict__ bkp,
                           const float* __restrict__ bv, float* __restrict__ biasC) {
  int i = blockIdx.x * 256 + threadIdx.x;
  if (i >= 2304) return;
  biasC[i] = i < 768 ? bqp[i] : (i < 1536 ? bkp[i - 768] : bv[i - 1536]);
}

// ---------- K4: bf16 GEMM + fused maxexp epilogue ----------
// C = A_bf16 @ B^T + bias, 128x128 tile, BK=32, 4 waves x (4x4) mfma.
// q cols -> qp [bh][s][64]; k cols -> exp features TRANSPOSED kpT [bh][m][n];
// v cols -> vT [bh][d][n].
__global__ __launch_bounds__(256, 4) void gemm_qkv(
    const U16* __restrict__ Ahi, const U16* __restrict__ Bhi,
    const float* __restrict__ bias,
    U16* __restrict__ qp, U16* __restrict__ kpT, U16* __restrict__ vT) {
  __shared__ __align__(16) U16 Us[2 * 128 * 32];
  const int tid = threadIdx.x, w = tid >> 6, lane = tid & 63;
  const int quad = lane >> 4, l16 = lane & 15;
  const int rowA0 = blockIdx.y * 128, colB0 = blockIdx.x * 128;
  const int wm = w & 1, wn = w >> 1;
  const int K = 768;
  f32x4 acc[4][4] = {};
  const U16* srcs[4];
  unsigned ldsoff[4];
#pragma unroll
  for (int t = 0; t < 4; ++t) {
    int c = w * 4 + t, cc = c & 7, buf = c >> 3;
    const U16* base = buf ? Bhi : Ahi;
    int r0 = buf ? colB0 : rowA0;
    srcs[t] = base + (size_t)(r0 + cc * 16 + (lane >> 2)) * K + (lane & 3) * 8;
    ldsoff[t] = c * 512;
  }
  for (int k0 = 0; k0 < K; k0 += 32) {
#pragma unroll
    for (int t = 0; t < 4; ++t) gl2lds16(srcs[t] + k0, &Us[ldsoff[t]]);
    __syncthreads();
    bf16x8 ah[4];
#pragma unroll
    for (int i = 0; i < 4; ++i)
      ah[i] = *(const bf16x8*)&Us[(wm * 64 + i * 16 + l16) * 32 + quad * 8];
#pragma unroll
    for (int j = 0; j < 4; ++j) {
      bf16x8 bh = *(const bf16x8*)&Us[4096 + (wn * 64 + j * 16 + l16) * 32 + quad * 8];
#pragma unroll
      for (int i = 0; i < 4; ++i)
        acc[i][j] = __builtin_amdgcn_mfma_f32_16x16x32_bf16(ah[i], bh, acc[i][j], 0, 0, 0);
    }
    __syncthreads();
  }
  // epilogue: each wave's 64-col half is one head block
  const int col64 = colB0 + wn * 64;
  float bj[4];
#pragma unroll
  for (int j = 0; j < 4; ++j) bj[j] = bias[col64 + j * 16 + l16];
  if (col64 < 768) {                            // q logits -> row-major qp
    const int h = col64 >> 6;
#pragma unroll
    for (int i = 0; i < 4; ++i) {
#pragma unroll
      for (int r = 0; r < 4; ++r) {
        int row = rowA0 + wm * 64 + i * 16 + quad * 4 + r;
        float v0 = acc[i][0][r] + bj[0], v1 = acc[i][1][r] + bj[1];
        float v2 = acc[i][2][r] + bj[2], v3 = acc[i][3][r] + bj[3];
        float mx = fmaxf(fmaxf(v0, v1), fmaxf(v2, v3));
        mx = fmaxf(mx, __shfl_xor(mx, 1));
        mx = fmaxf(mx, __shfl_xor(mx, 2));
        mx = fmaxf(mx, __shfl_xor(mx, 4));
        mx = fmaxf(mx, __shfl_xor(mx, 8));
        int b = row >> 13, s = row & 8191;
        size_t base = ((size_t)(b * NH_ + h) * S_ + s) * 64 + l16;
        qp[base +  0] = f2b(__expf(v0 - mx));
        qp[base + 16] = f2b(__expf(v1 - mx));
        qp[base + 32] = f2b(__expf(v2 - mx));
        qp[base + 48] = f2b(__expf(v3 - mx));
      }
    }
  } else {                                      // k (exp) or v -> transposed
    const int isv = col64 >= 1536;
    const int h = (col64 - (isv ? 1536 : 768)) >> 6;
    U16* dstT = isv ? vT : kpT;
#pragma unroll
    for (int i = 0; i < 4; ++i) {
      float er[4][4];                           // [j][r]
#pragma unroll
      for (int r = 0; r < 4; ++r) {
        float v0 = acc[i][0][r] + bj[0], v1 = acc[i][1][r] + bj[1];
        float v2 = acc[i][2][r] + bj[2], v3 = acc[i][3][r] + bj[3];
        if (!isv) {
          float mx = fmaxf(fmaxf(v0, v1), fmaxf(v2, v3));
          mx = fmaxf(mx, __shfl_xor(mx, 1));
          mx = fmaxf(mx, __shfl_xor(mx, 2));
          mx = fmaxf(mx, __shfl_xor(mx, 4));
          mx = fmaxf(mx, __shfl_xor(mx, 8));
          v0 = __expf(v0 - mx); v1 = __expf(v1 - mx);
          v2 = __expf(v2 - mx); v3 = __expf(v3 - mx);
        }
        er[0][r] = v0; er[1][r] = v1; er[2][r] = v2; er[3][r] = v3;
      }
      int n = rowA0 + wm * 64 + i * 16 + quad * 4;   // r=0 row (4-aligned, no batch cross)
      int b = n >> 13, s = n & 8191;
      int bh = b * NH_ + h;
#pragma unroll
      for (int j = 0; j < 4; ++j) {
        ushort4 o;
        o.x = f2b(er[j][0]); o.y = f2b(er[j][1]);
        o.z = f2b(er[j][2]); o.w = f2b(er[j][3]);
        *(ushort4*)&dstT[((size_t)bh * 64 + j * 16 + l16) * S_ + s] = o;
      }
    }
  }
}

// ---------- K5: kv summary via MFMA: kvT[bh][d][m], row 64 = ksum ----------
// grid (8, 48). A-role = vT rows (d), B-role = kpT rows (m), K = n (1024/block).
__global__ __launch_bounds__(256, 4) void kv_accum_mfma(
    const U16* __restrict__ kpT, const U16* __restrict__ vT,
    float* __restrict__ kvT) {
  __shared__ __align__(16) U16 Us[2 * 64 * 64];   // [0:4096]=vT tile, [4096:8192]=kpT tile
  const int tid = threadIdx.x, w = tid >> 6, lane = tid & 63;
  const int quad = lane >> 4, l16 = lane & 15;
  const int bh = blockIdx.y;
  const int n0 = blockIdx.x * 1024;
  const U16* srcs[4];
  unsigned ldsoff[4];
#pragma unroll
  for (int t = 0; t < 4; ++t) {
    int c = w * 4 + t, buf = c >> 3;              // 0..15; buf 0 = vT, 1 = kpT
    int r = (c & 7) * 8 + (lane >> 3);
    const U16* base = buf ? kpT : vT;
    srcs[t] = base + ((size_t)bh * 64 + r) * S_ + n0 + (lane & 7) * 8;
    ldsoff[t] = buf * 4096 + (c & 7) * 512;
  }
  f32x4 acc[4] = {};
  float ks[4] = {0.f, 0.f, 0.f, 0.f};
  for (int nc = 0; nc < 1024; nc += 64) {
#pragma unroll
    for (int t = 0; t < 4; ++t) gl2lds16(srcs[t] + nc, &Us[ldsoff[t]]);
    __syncthreads();
#pragma unroll
    for (int k0 = 0; k0 < 64; k0 += 32) {
      bf16x8 av = *(const bf16x8*)&Us[(w * 16 + l16) * 64 + k0 + quad * 8];
#pragma unroll
      for (int j = 0; j < 4; ++j) {
        bf16x8 bk = *(const bf16x8*)&Us[4096 + (j * 16 + l16) * 64 + k0 + quad * 8];
        if (w == 0) {
#pragma unroll
          for (int e = 0; e < 8; ++e) ks[j] += b2f((U16)bk[e]);
        }
        acc[j] = __builtin_amdgcn_mfma_f32_16x16x32_bf16(av, bk, acc[j], 0, 0, 0);
      }
    }
    __syncthreads();
  }
#pragma unroll
  for (int j = 0; j < 4; ++j)
#pragma unroll
    for (int r = 0; r < 4; ++r) {
      int d = w * 16 + quad * 4 + r;
      atomicAdd(&kvT[((size_t)bh * 80 + d) * 64 + j * 16 + l16], acc[j][r]);
    }
  if (w == 0) {
#pragma unroll
    for (int j = 0; j < 4; ++j) {
      ks[j] += __shfl_xor(ks[j], 16);
      ks[j] += __shfl_xor(ks[j], 32);
    }
    if (lane < 16) {
#pragma unroll
      for (int j = 0; j < 4; ++j)
        atomicAdd(&kvT[((size_t)bh * 80 + 64) * 64 + j * 16 + lane], ks[j]);
    }
  }
}

// ---------- K6: ctx = (qp @ kv)/(norm+eps); norm = MFMA tile j=4 ----------
__global__ __launch_bounds__(256) void ctx_gemm_k(
    const U16* __restrict__ qp, const float* __restrict__ kvT,
    U16* __restrict__ ctx) {
  __shared__ __align__(16) U16 As[128 * 64];
  __shared__ __align__(16) U16 Bs[80 * 64];
  int bh = blockIdx.y, row0 = blockIdx.x * 128;
  int tid = threadIdx.x, w = tid >> 6, lane = tid & 63;
  int quad = lane >> 4, l16 = lane & 15;
  const U16* Ab = qp + ((size_t)bh * S_ + row0) * 64;
#pragma unroll
  for (int t = 0; t < 4; ++t) {
    int cb = (w * 4 + t) * 64;
    gl2lds16(Ab + (size_t)(cb + lane) * 8, &As[cb * 8]);
  }
  const float4* kv4 = (const float4*)(kvT + (size_t)bh * 5120);
#pragma unroll
  for (int t = 0; t < 5; ++t) {
    int idx = t * 256 + tid;          // 1280 float4s = 80*64 floats
    float4 f = kv4[idx];
    ushort4 o;
    o.x = f2b(f.x); o.y = f2b(f.y); o.z = f2b(f.z); o.w = f2b(f.w);
    *(ushort4*)&Bs[idx * 4] = o;
  }
  __syncthreads();
  f32x4 acc[2][5] = {};
#pragma unroll
  for (int k0 = 0; k0 < 64; k0 += 32) {
    bf16x8 a[2], fb[5];
#pragma unroll
    for (int i = 0; i < 2; ++i)
      a[i] = *(const bf16x8*)&As[(w * 32 + i * 16 + l16) * 64 + k0 + quad * 8];
#pragma unroll
    for (int j = 0; j < 5; ++j)
      fb[j] = *(const bf16x8*)&Bs[(j * 16 + l16) * 64 + k0 + quad * 8];
#pragma unroll
    for (int j = 0; j < 5; ++j)
#pragma unroll
      for (int i = 0; i < 2; ++i)
        acc[i][j] = __builtin_amdgcn_mfma_f32_16x16x32_bf16(a[i], fb[j], acc[i][j], 0, 0, 0);
  }
  int b = bh / NH_, h = bh - b * NH_;
#pragma unroll
  for (int i = 0; i < 2; ++i) {
#pragma unroll
    for (int r = 0; r < 4; ++r) {
      int s = row0 + w * 32 + i * 16 + quad * 4 + r;
      float nv = __shfl(acc[i][4][r], lane & 48);   // col 64 (l16==0) = norm(row)
      float inv = 1.f / (nv + EPS_);
      size_t base = ((size_t)b * S_ + s) * H_ + h * 64;
#pragma unroll
      for (int j = 0; j < 4; ++j)
        ctx[base + j * 16 + l16] = f2b(acc[i][j][r] * inv);
    }
  }
}

// ---------- K7: bf16 GEMM (output projection) ----------
__global__ __launch_bounds__(256, 4) void gemm_out(
    const U16* __restrict__ Ahi, const U16* __restrict__ Bhi,
    const float* __restrict__ bias, float* __restrict__ C, int K, int ldc) {
  __shared__ __align__(16) U16 Us[2 * 128 * 32];
  const int tid = threadIdx.x, w = tid >> 6, lane = tid & 63;
  const int quad = lane >> 4, l16 = lane & 15;
  const int rowA0 = blockIdx.y * 128, colB0 = blockIdx.x * 128;
  const int wm = w & 1, wn = w >> 1;
  f32x4 acc[4][4] = {};
  const U16* srcs[4];
  unsigned ldsoff[4];
#pragma unroll
  for (int t = 0; t < 4; ++t) {
    int c = w * 4 + t, cc = c & 7, buf = c >> 3;
    const U16* base = buf ? Bhi : Ahi;
    int r0 = buf ? colB0 : rowA0;
    srcs[t] = base + (size_t)(r0 + cc * 16 + (lane >> 2)) * K + (lane & 3) * 8;
    ldsoff[t] = c * 512;
  }
  for (int k0 = 0; k0 < K; k0 += 32) {
#pragma unroll
    for (int t = 0; t < 4; ++t) gl2lds16(srcs[t] + k0, &Us[ldsoff[t]]);
    __syncthreads();
    bf16x8 ah[4];
#pragma unroll
    for (int i = 0; i < 4; ++i)
      ah[i] = *(const bf16x8*)&Us[(wm * 64 + i * 16 + l16) * 32 + quad * 8];
#pragma unroll
    for (int j = 0; j < 4; ++j) {
      bf16x8 bh = *(const bf16x8*)&Us[4096 + (wn * 64 + j * 16 + l16) * 32 + quad * 8];
#pragma unroll
      for (int i = 0; i < 4; ++i)
        acc[i][j] = __builtin_amdgcn_mfma_f32_16x16x32_bf16(ah[i], bh, acc[i][j], 0, 0, 0);
    }
    __syncthreads();
  }
#pragma unroll
  for (int i = 0; i < 4; ++i) {
    int row = rowA0 + wm * 64 + i * 16 + quad * 4;
#pragma unroll
    for (int j = 0; j < 4; ++j) {
      int col = colB0 + wn * 64 + j * 16 + l16;
      float bvv = bias[col];
#pragma unroll
      for (int r = 0; r < 4; ++r)
        C[(size_t)(row + r) * ldc + col] = acc[i][j][r] + bvv;
    }
  }
}

extern "C" void kernel_launch(void* const* d_in, const int* in_sizes, int n_in,
                              void* d_out, int out_size, void* d_ws, size_t ws_size,
                              hipStream_t stream) {
  const float* hs = (const float*)d_in[0];
  const float* Wq = (const float*)d_in[1];
  const float* bq = (const float*)d_in[2];
  const float* Wk = (const float*)d_in[3];
  const float* bk = (const float*)d_in[4];
  const float* Wv = (const float*)d_in[5];
  const float* bv = (const float*)d_in[6];
  const float* Wo = (const float*)d_in[7];
  const float* bo = (const float*)d_in[8];
  const float* P  = (const float*)d_in[9];
  float* out = (float*)d_out;

  char* ws = (char*)d_ws;
  size_t off = 0;
  auto alloc = [&](size_t bytes) -> void* {
    void* p = ws + off;
    off = (off + bytes + 255) & ~(size_t)255;
    return p;
  };
  U16*   hs_hi = (U16*)alloc(50331648);     // [32768,768] bf16 (reused as ctx)
  float* WqpF  = (float*)alloc(2359296);
  float* WkpF  = (float*)alloc(2359296);
  float* bqpF  = (float*)alloc(3072);
  float* bkpF  = (float*)alloc(3072);
  U16*   WcatH = (U16*)alloc(3538944);      // [2304,768] bf16
  U16*   WoTH  = (U16*)alloc(1179648);
  float* biasC = (float*)alloc(9216);
  U16*   qp    = (U16*)alloc(50331648);     // [48,8192,64] bf16 row-major
  U16*   kpT   = (U16*)alloc(50331648);     // [48,64,8192] bf16 transposed
  U16*   vT    = (U16*)alloc(50331648);     // [48,64,8192] bf16 transposed
  float* kvT   = (float*)alloc(983040);     // [48,80,64] fp32 (row 64 = ksum)
  U16*   ctx   = hs_hi;                     // hs dead after QKV GEMM: reuse

  zero_f32<<<dim3(960), dim3(256), 0, stream>>>(kvT, 245760);
  cvt_f32_bf16<<<dim3(24576), dim3(256), 0, stream>>>(hs, hs_hi, 6291456);
  fold_proj<<<dim3(192, 12, 2), dim3(256), 0, stream>>>(Wq, bq, Wk, bk, P, WqpF, bqpF, WkpF, bkpF);
  build_cat<<<dim3(3, 3072), dim3(256), 0, stream>>>(WqpF, WkpF, Wv, Wo, WcatH, WoTH);
  build_bias<<<dim3(9), dim3(256), 0, stream>>>(bqpF, bkpF, bv, biasC);
  gemm_qkv<<<dim3(18, 256), dim3(256), 0, stream>>>(hs_hi, WcatH, biasC, qp, kpT, vT);
  kv_accum_mfma<<<dim3(8, 48), dim3(256), 0, stream>>>(kpT, vT, kvT);
  ctx_gemm_k<<<dim3(64, 48), dim3(256), 0, stream>>>(qp, kvT, ctx);
  gemm_out<<<dim3(6, 256), dim3(256), 0, stream>>>(ctx, WoTH, bo, out, 768, 768);
}